// Round 1
// baseline (348.429 us; speedup 1.0000x reference)
//
#include <hip/hip_runtime.h>
#include <math.h>

#define B_N 2048
#define KK 128
#define MM 640
#define ALPHA (1.0f/128.0f)
#define VARTHETA 0.1f
#define PMAXV 10.0f
#define BIGV 1000000000.0f

// hw LDS swizzle: quad q of row i stored at slot (q+i)&31; row stride 128 (no pad).
// hw[i][j] -> hw[i*128 + (((j>>2)+i)&31)*4 + (j&3)]

__global__ __launch_bounds__(512, 1)
void unfold_pocs_kernel(
    const int* __restrict__ num_itr_p, const int* __restrict__ kth_p,
    const float* __restrict__ HW, const float* __restrict__ x0,
    const float* __restrict__ nu3_p, const float* __restrict__ tg_p,
    const float* __restrict__ g1_W0a, const float* __restrict__ g1_W1a,
    const float* __restrict__ g1_W0b, const float* __restrict__ g1_W1b,
    const float* __restrict__ g2_W0a, const float* __restrict__ g2_W1a,
    const float* __restrict__ g2_W0b, const float* __restrict__ g2_W1b,
    float* __restrict__ out)
{
    __shared__ __align__(16) float hw[KK*KK];      // 64 KB, swizzled
    __shared__ __align__(16) float c2s[KK*36];     // C2 = W0a_top + HW@W1a_top + X2@W1a_bot
    __shared__ __align__(16) float zs[KK*36];      // W1a_top staging, then Z2
    __shared__ __align__(16) float e5[KK*8];       // E = Z2 @ W1b2
    __shared__ __align__(16) float xb[MM];
    __shared__ __align__(16) float g1w0a[160], g1w1a[160];
    __shared__ __align__(16) float g1w0b[64],  g1w1b[64];
    __shared__ __align__(16) float w0a2b[160], w1a2b[160];   // bottom 5 rows of g2 W0a/W1a
    __shared__ __align__(16) float w0b2[160],  w1b2[160];    // 32x5
    __shared__ float red[16];
    __shared__ float lbd_l[2];
    __shared__ float fval_l;

    const int t = threadIdx.x;
    const int b = blockIdx.x;
    const float* HWb = HW + (size_t)b * (KK*KK);

    // ---------- staging ----------
    #pragma unroll
    for (int it = 0; it < 8; ++it) {
        int qi = it * 512 + t;          // 4096 quads = 128 rows * 32 slots
        int row = qi >> 5, slot = qi & 31;
        int q = (slot - row) & 31;
        float4 v = *(const float4*)(HWb + row*KK + q*4);
        *(float4*)(hw + row*KK + slot*4) = v;
    }
    if (t < 160) {
        *(float4*)(xb + t*4) = *(const float4*)(x0 + (size_t)b*MM + t*4);
        g1w0a[t] = g1_W0a[t];
        g1w1a[t] = g1_W1a[t];
        w0a2b[t] = g2_W0a[KK*32 + t];
        w1a2b[t] = g2_W1a[KK*32 + t];
        w0b2[t]  = g2_W0b[t];
        w1b2[t]  = g2_W1b[t];
    }
    if (t < 64) { g1w0b[t] = g1_W0b[t]; g1w1b[t] = g1_W1b[t]; }
    {   // stage W1a2_top (128x32) into zs (row stride 36)
        int j = t >> 2, h4 = (t & 3) * 8;
        *(float4*)(zs + j*36 + h4)     = *(const float4*)(g2_W1a + j*32 + h4);
        *(float4*)(zs + j*36 + h4 + 4) = *(const float4*)(g2_W1a + j*32 + h4 + 4);
    }
    __syncthreads();

    const int row = t >> 2, g = t & 3;   // 4 lanes per row for row-ops

    // ---------- g1: lbd ----------
    float sx[5] = {0,0,0,0,0};
    for (int w = 0; w < 32; ++w) {
        int jj = 4*w + g;
        float hv = hw[row*KK + (((w + row) & 31) << 2) + g];   // hw[row][jj]
        #pragma unroll
        for (int f = 0; f < 5; ++f) sx[f] += hv * xb[f*KK + jj];
    }
    #pragma unroll
    for (int f = 0; f < 5; ++f) { sx[f] += __shfl_xor(sx[f], 1); sx[f] += __shfl_xor(sx[f], 2); }

    float x1r[5];
    #pragma unroll
    for (int f = 0; f < 5; ++f) x1r[f] = xb[f*KK + row];

    float zb0p0=0, zb0p1=0, zb1p0=0, zb1p1=0;
    #pragma unroll
    for (int hh = 0; hh < 8; ++hh) {
        int h = 8*g + hh;
        float a = 0.0f;
        #pragma unroll
        for (int f = 0; f < 5; ++f) a += x1r[f]*g1w0a[f*32+h] + sx[f]*g1w1a[f*32+h];
        a = fmaxf(a, 0.0f);
        zb0p0 += a * g1w0b[h*2+0];
        zb0p1 += a * g1w0b[h*2+1];
        zb1p0 += a * g1w1b[h*2+0];
        zb1p1 += a * g1w1b[h*2+1];
    }
    float mp = 0.0f;           // column sum of hw column 'row'
    for (int w = 0; w < 32; ++w) {
        int i = 4*w + g;
        mp += hw[i*KK + ((((row >> 2) + i) & 31) << 2) + (row & 3)];
    }
    mp += __shfl_xor(mp, 1); mp += __shfl_xor(mp, 2);
    float m = mp * (1.0f/KK);
    float c0 = zb0p0*(1.0f/KK) + m*zb1p0;
    float c1 = zb0p1*(1.0f/KK) + m*zb1p1;
    #pragma unroll
    for (int s = 1; s < 64; s <<= 1) { c0 += __shfl_xor(c0, s); c1 += __shfl_xor(c1, s); }
    if ((t & 63) == 0) { red[(t>>6)*2] = c0; red[(t>>6)*2 + 1] = c1; }
    __syncthreads();
    if (t == 0) {
        float a0=0, a1=0;
        for (int w2 = 0; w2 < 8; ++w2) { a0 += red[w2*2]; a1 += red[w2*2+1]; }
        lbd_l[0] = fmaxf(a0, 0.0f);
        lbd_l[1] = fmaxf(a1, 0.0f);
    }
    __syncthreads();

    // ---------- x update (s1, s4) ----------
    if (t < KK) {
        float s1v = xb[KK + t];
        xb[KK + t]   = s1v - lbd_l[0] * (ALPHA / (1.0f + s1v));
        xb[4*KK + t] += lbd_l[1] * (ALPHA * VARTHETA);
    }
    __syncthreads();

    // ---------- c2 init = W0a_top + X2 @ W1a_bot ----------
    {
        int i = t >> 2, hb = (t & 3) * 8;
        float x2r[5];
        #pragma unroll
        for (int f = 0; f < 5; ++f) x2r[f] = xb[f*KK + i];
        #pragma unroll
        for (int hh = 0; hh < 8; ++hh) {
            int h = hb + hh;
            float a = g2_W0a[i*32 + h];
            #pragma unroll
            for (int f = 0; f < 5; ++f) a += x2r[f] * w1a2b[f*32 + h];
            c2s[i*36 + h] = a;
        }
    }
    __syncthreads();

    // ---------- matmul 1: c2 += hw @ W1a_top(zs) ----------
    const int rt   = t & 31;
    const int cob  = ((t >> 5) & 7) << 2;
    const int half = t >> 8;

    float acc[4][4];
    #pragma unroll
    for (int s = 0; s < 4; ++s)
        #pragma unroll
        for (int c = 0; c < 4; ++c) acc[s][c] = 0.0f;

    for (int jq = half*16; jq < half*16 + 16; ++jq) {
        int slot = (jq + rt) & 31;
        float hq[4][4], cq[4][4];
        #pragma unroll
        for (int s = 0; s < 4; ++s)
            *(float4*)hq[s] = *(const float4*)(hw + (rt + 32*s)*KK + slot*4);
        #pragma unroll
        for (int u = 0; u < 4; ++u)
            *(float4*)cq[u] = *(const float4*)(zs + (4*jq + u)*36 + cob);
        #pragma unroll
        for (int u = 0; u < 4; ++u)
            #pragma unroll
            for (int s = 0; s < 4; ++s) {
                float hv = hq[s][u];
                #pragma unroll
                for (int c = 0; c < 4; ++c) acc[s][c] += hv * cq[u][c];
            }
    }
    if (half == 0) {
        #pragma unroll
        for (int s = 0; s < 4; ++s) {
            float4 v = *(float4*)(c2s + (rt + 32*s)*36 + cob);
            v.x += acc[s][0]; v.y += acc[s][1]; v.z += acc[s][2]; v.w += acc[s][3];
            *(float4*)(c2s + (rt + 32*s)*36 + cob) = v;
        }
    }
    __syncthreads();
    if (half == 1) {
        #pragma unroll
        for (int s = 0; s < 4; ++s) {
            float4 v = *(float4*)(c2s + (rt + 32*s)*36 + cob);
            v.x += acc[s][0]; v.y += acc[s][1]; v.z += acc[s][2]; v.w += acc[s][3];
            *(float4*)(c2s + (rt + 32*s)*36 + cob) = v;
        }
    }
    __syncthreads();

    // ---------- matmul 2: zs = relu(hw @ c2 + X2 @ W0a_bot) ----------
    #pragma unroll
    for (int s = 0; s < 4; ++s)
        #pragma unroll
        for (int c = 0; c < 4; ++c) acc[s][c] = 0.0f;
    if (half == 0) {
        #pragma unroll
        for (int s = 0; s < 4; ++s) {
            int i = rt + 32*s;
            float x2r[5];
            #pragma unroll
            for (int f = 0; f < 5; ++f) x2r[f] = xb[f*KK + i];
            #pragma unroll
            for (int c = 0; c < 4; ++c) {
                float a = 0.0f;
                #pragma unroll
                for (int f = 0; f < 5; ++f) a += x2r[f] * w0a2b[f*32 + cob + c];
                acc[s][c] = a;
            }
        }
    }
    for (int jq = half*16; jq < half*16 + 16; ++jq) {
        int slot = (jq + rt) & 31;
        float hq[4][4], cq[4][4];
        #pragma unroll
        for (int s = 0; s < 4; ++s)
            *(float4*)hq[s] = *(const float4*)(hw + (rt + 32*s)*KK + slot*4);
        #pragma unroll
        for (int u = 0; u < 4; ++u)
            *(float4*)cq[u] = *(const float4*)(c2s + (4*jq + u)*36 + cob);
        #pragma unroll
        for (int u = 0; u < 4; ++u)
            #pragma unroll
            for (int s = 0; s < 4; ++s) {
                float hv = hq[s][u];
                #pragma unroll
                for (int c = 0; c < 4; ++c) acc[s][c] += hv * cq[u][c];
            }
    }
    if (half == 0) {   // write raw partials (overwrites W1a_top; matmul1 done)
        #pragma unroll
        for (int s = 0; s < 4; ++s) {
            float4 v;
            v.x = acc[s][0]; v.y = acc[s][1]; v.z = acc[s][2]; v.w = acc[s][3];
            *(float4*)(zs + (rt + 32*s)*36 + cob) = v;
        }
    }
    __syncthreads();
    if (half == 1) {   // add + relu
        #pragma unroll
        for (int s = 0; s < 4; ++s) {
            float4 v = *(float4*)(zs + (rt + 32*s)*36 + cob);
            v.x = fmaxf(v.x + acc[s][0], 0.0f);
            v.y = fmaxf(v.y + acc[s][1], 0.0f);
            v.z = fmaxf(v.z + acc[s][2], 0.0f);
            v.w = fmaxf(v.w + acc[s][3], 0.0f);
            *(float4*)(zs + (rt + 32*s)*36 + cob) = v;
        }
    }
    __syncthreads();

    // ---------- E = Z@W1b2, t0 = Z@W0b2 (per row, 4 lanes split over h) ----------
    float ev[5] = {0,0,0,0,0}, t0[5] = {0,0,0,0,0};
    #pragma unroll
    for (int hh = 0; hh < 8; ++hh) {
        int h = 8*g + hh;
        float zv = zs[row*36 + h];
        #pragma unroll
        for (int c = 0; c < 5; ++c) {
            ev[c] += zv * w1b2[h*5 + c];
            t0[c] += zv * w0b2[h*5 + c];
        }
    }
    #pragma unroll
    for (int c = 0; c < 5; ++c) {
        ev[c] += __shfl_xor(ev[c], 1); ev[c] += __shfl_xor(ev[c], 2);
        t0[c] += __shfl_xor(t0[c], 1); t0[c] += __shfl_xor(t0[c], 2);
    }
    if (g == 0) {
        #pragma unroll
        for (int c = 0; c < 5; ++c) e5[row*8 + c] = ev[c];
    }
    __syncthreads();

    // ---------- tilde = t0 + hw @ E ; x += tilde^T ----------
    float td[5] = {0,0,0,0,0};
    for (int w = 0; w < 32; ++w) {
        int jj = 4*w + g;
        float hv = hw[row*KK + (((w + row) & 31) << 2) + g];
        #pragma unroll
        for (int c = 0; c < 5; ++c) td[c] += hv * e5[jj*8 + c];
    }
    #pragma unroll
    for (int c = 0; c < 5; ++c) { td[c] += __shfl_xor(td[c], 1); td[c] += __shfl_xor(td[c], 2); }
    xb[g*KK + row] += t0[g] + td[g];
    if (g == 0) xb[4*KK + row] += t0[4] + td[4];
    __syncthreads();

    // ---------- f = sum(x[:K]) - PMAX ----------
    float pv = (t < KK) ? xb[t] : 0.0f;
    #pragma unroll
    for (int s = 1; s < 64; s <<= 1) pv += __shfl_xor(pv, s);
    if ((t & 63) == 0) red[t >> 6] = pv;
    __syncthreads();
    if (t == 0) {
        float fs = 0.0f;
        for (int w2 = 0; w2 < 8; ++w2) fs += red[w2];
        fval_l = fs - PMAXV;
    }
    __syncthreads();

    const int num_itr = num_itr_p[0], kth = kth_p[0];
    const bool flag = (kth == num_itr - 1);
    const float nu3 = nu3_p[0], tg = tg_p[0];
    const float onu = 1.0f + nu3, otg = 1.0f + tg;
    const float Vnu = 1.0f - 1.0f/(onu*onu), Vg = 1.0f - 1.0f/(otg*otg);
    const float fv = fval_l;
    float* outx = out + (size_t)b * MM;

    #pragma unroll
    for (int r2 = 0; r2 < 2; ++r2) {
        int idx = r2*512 + t;
        if (idx < MM) {
            float v = xb[idx];
            if (idx < KK && fv > 0.0f) v -= fv * (1.0f/KK);
            v = fmaxf(v, (idx >= KK   && idx < 2*KK) ? nu3 : 0.0f);
            v = fminf(v, (idx >= 2*KK && idx < 3*KK) ? tg  : BIGV);
            v = fmaxf(v, (idx >= 3*KK && idx < 4*KK) ? Vnu : 0.0f);
            v = fminf(v, (idx >= 3*KK && idx < 4*KK) ? Vg  : BIGV);
            if (flag) v = fmaxf(v, 0.0f);
            xb[idx] = v;
            outx[idx] = v;
        }
    }
    __syncthreads();

    if (flag) {
        const size_t O1 = (size_t)B_N*MM;
        const size_t OK = (size_t)B_N*KK;
        if (t < KK) {
            float xg = xb[2*KK + t], xv = xb[3*KK + t];
            float u1 = 1.0f + xg;
            out[O1 + (size_t)b*KK + t]      = 1.0f - 1.0f/(u1*u1) - xv;   // f5
            out[O1 + OK + (size_t)b*KK + t] = sqrtf(xv) - xb[4*KK + t];   // f6
        }
        float dp = 0.0f;    // sum_i p[i]*hw[i][row]
        for (int w = 0; w < 32; ++w) {
            int i = 4*w + g;
            dp += xb[i] * hw[i*KK + ((((row >> 2) + i) & 31) << 2) + (row & 3)];
        }
        dp += __shfl_xor(dp, 1); dp += __shfl_xor(dp, 2);
        if (g == 0) {
            float p = xb[row], nuv = xb[KK + row], xg = xb[2*KK + row];
            float diag = hw[row*KK + ((((row >> 2) + row) & 31) << 2) + (row & 3)];
            float top = p * diag;
            float down = dp - top + 1.0f;
            out[O1 + 2*OK + (size_t)b*KK + row] = top - down * xg;        // f4
            out[O1 + 3*OK + (size_t)b*KK + row] = nuv * down - top;       // f2
        }
    }
}

extern "C" void kernel_launch(void* const* d_in, const int* in_sizes, int n_in,
                              void* d_out, int out_size, void* d_ws, size_t ws_size,
                              hipStream_t stream) {
    unfold_pocs_kernel<<<dim3(B_N), dim3(512), 0, stream>>>(
        (const int*)d_in[0], (const int*)d_in[1],
        (const float*)d_in[2], (const float*)d_in[3],
        (const float*)d_in[4], (const float*)d_in[5],
        (const float*)d_in[12], (const float*)d_in[13],
        (const float*)d_in[14], (const float*)d_in[15],
        (const float*)d_in[16], (const float*)d_in[17],
        (const float*)d_in[18], (const float*)d_in[19],
        (float*)d_out);
}

// Round 2
// 258.639 us; speedup vs baseline: 1.3472x; 1.3472x over previous
//
#include <hip/hip_runtime.h>
#include <math.h>

#define B_N 2048
#define KK 128
#define MM 640
#define HS 136   // bf16 element stride for MFMA-staged rows (pad breaks bank conflicts)
#define ZS 40    // Z row stride (bf16)
#define ALPHA (1.0f/128.0f)
#define VARTHETA 0.1f
#define PMAXV 10.0f
#define BIGV 1000000000.0f

typedef __attribute__((ext_vector_type(8))) short short8;
typedef __attribute__((ext_vector_type(4))) float floatx4;

static __device__ __forceinline__ unsigned short f2bf(float f) {
    unsigned u = __builtin_bit_cast(unsigned, f);
    u += 0x7fffu + ((u >> 16) & 1u);           // round-to-nearest-even
    return (unsigned short)(u >> 16);
}
static __device__ __forceinline__ float bf2f(unsigned short h) {
    unsigned u = ((unsigned)h) << 16;
    return __builtin_bit_cast(float, u);
}

__global__ __launch_bounds__(512, 4)
void unfold_pocs_kernel(
    const int* __restrict__ num_itr_p, const int* __restrict__ kth_p,
    const float* __restrict__ HW, const float* __restrict__ x0,
    const float* __restrict__ nu3_p, const float* __restrict__ tg_p,
    const float* __restrict__ g1_W0a, const float* __restrict__ g1_W1a,
    const float* __restrict__ g1_W0b, const float* __restrict__ g1_W1b,
    const float* __restrict__ g2_W0a, const float* __restrict__ g2_W1a,
    const float* __restrict__ g2_W0b, const float* __restrict__ g2_W1b,
    float* __restrict__ out)
{
    __shared__ __align__(16) unsigned short hwb[KK*HS];    // 34816 B, bf16 hw
    __shared__ __align__(16) unsigned short w1aT[32*HS];   // 8704 B, W1a_top^T
    __shared__ __align__(16) unsigned short c2T[32*HS];    // 8704 B, C2^T
    __shared__ __align__(16) unsigned short zb[KK*ZS];     // 10240 B, Z row-major
    __shared__ __align__(16) unsigned short eT[5*HS];      // 1360 B, E^T
    __shared__ __align__(16) float scr8[KK*8];             // 4096 B: SX, then t0
    __shared__ __align__(16) float xb[MM];
    __shared__ __align__(16) float g1w0a[160], g1w1a[160];
    __shared__ __align__(16) float g1w0b[64],  g1w1b[64];
    __shared__ __align__(16) float w0a2b[160], w1a2b[160]; // bottom 5 rows of g2 W0a/W1a
    __shared__ __align__(16) float w0b2[160],  w1b2[160];  // 32x5
    __shared__ float red[16];
    __shared__ float lbd_l[2];
    __shared__ float fval_l;

    const int t = threadIdx.x;
    const int b = blockIdx.x;
    const float* HWb = HW + (size_t)b * (KK*KK);

    // ---------- staging ----------
    #pragma unroll
    for (int it = 0; it < 8; ++it) {            // hw -> bf16 LDS (row-major, stride HS)
        int qi = it * 512 + t;                  // 4096 float4-quads
        int row = qi >> 5, q = qi & 31;
        float4 v = *(const float4*)(HWb + row*KK + q*4);
        ushort4 p4;
        p4.x = f2bf(v.x); p4.y = f2bf(v.y); p4.z = f2bf(v.z); p4.w = f2bf(v.w);
        *(ushort4*)&hwb[row*HS + q*4] = p4;
    }
    #pragma unroll
    for (int it = 0; it < 8; ++it) {            // W1a_top (128x32) -> transposed bf16
        int idx = it * 512 + t;
        int k = idx >> 5, n = idx & 31;
        w1aT[n*HS + k] = f2bf(g2_W1a[k*32 + n]);
    }
    if (t < 160) {
        *(float4*)(xb + t*4) = *(const float4*)(x0 + (size_t)b*MM + t*4);
        g1w0a[t] = g1_W0a[t];
        g1w1a[t] = g1_W1a[t];
        w0a2b[t] = g2_W0a[KK*32 + t];
        w1a2b[t] = g2_W1a[KK*32 + t];
        w0b2[t]  = g2_W0b[t];
        w1b2[t]  = g2_W1b[t];
    }
    if (t < 64) { g1w0b[t] = g1_W0b[t]; g1w1b[t] = g1_W1b[t]; }
    __syncthreads();

    const int wv = t >> 6, lane = t & 63, quad = lane >> 4, lr = lane & 15;

    // ---------- SX = HW @ X1 via MFMA (N=16, cols 0..4 valid) ----------
    {
        floatx4 acc = {0.f, 0.f, 0.f, 0.f};
        const int ns = lr < 5 ? lr : 4;
        #pragma unroll
        for (int kt = 0; kt < 4; ++kt) {
            short8 a = *(const short8*)&hwb[(wv*16 + lr)*HS + kt*32 + quad*8];
            float4 f0 = *(const float4*)(xb + ns*KK + kt*32 + quad*8);
            float4 f1 = *(const float4*)(xb + ns*KK + kt*32 + quad*8 + 4);
            short8 bb;
            bb[0]=(short)f2bf(f0.x); bb[1]=(short)f2bf(f0.y); bb[2]=(short)f2bf(f0.z); bb[3]=(short)f2bf(f0.w);
            bb[4]=(short)f2bf(f1.x); bb[5]=(short)f2bf(f1.y); bb[6]=(short)f2bf(f1.z); bb[7]=(short)f2bf(f1.w);
            acc = __builtin_amdgcn_mfma_f32_16x16x32_bf16(a, bb, acc, 0, 0, 0);
        }
        if (lr < 5) {
            #pragma unroll
            for (int r = 0; r < 4; ++r)
                scr8[(wv*16 + quad*4 + r)*8 + lr] = acc[r];   // SX[m][f]
        }
    }
    __syncthreads();

    const int row = t >> 2, g = t & 3;   // 4 lanes per row for row-ops

    // ---------- g1: lbd ----------
    {
        float sx[5], x1r[5];
        #pragma unroll
        for (int f = 0; f < 5; ++f) { sx[f] = scr8[row*8 + f]; x1r[f] = xb[f*KK + row]; }

        float zb0p0=0, zb0p1=0, zb1p0=0, zb1p1=0;
        #pragma unroll
        for (int hh = 0; hh < 8; ++hh) {
            int h = 8*g + hh;
            float a = 0.0f;
            #pragma unroll
            for (int f = 0; f < 5; ++f) a += x1r[f]*g1w0a[f*32+h] + sx[f]*g1w1a[f*32+h];
            a = fmaxf(a, 0.0f);
            zb0p0 += a * g1w0b[h*2+0];
            zb0p1 += a * g1w0b[h*2+1];
            zb1p0 += a * g1w1b[h*2+0];
            zb1p1 += a * g1w1b[h*2+1];
        }
        float mp = 0.0f;                    // column sum of hw column 'row'
        for (int w = 0; w < 32; ++w) {
            int i = 4*w + g;
            mp += bf2f(hwb[i*HS + row]);
        }
        mp += __shfl_xor(mp, 1); mp += __shfl_xor(mp, 2);
        float m = mp * (1.0f/KK);
        float c0 = zb0p0*(1.0f/KK) + m*zb1p0;
        float c1 = zb0p1*(1.0f/KK) + m*zb1p1;
        #pragma unroll
        for (int s = 1; s < 64; s <<= 1) { c0 += __shfl_xor(c0, s); c1 += __shfl_xor(c1, s); }
        if ((t & 63) == 0) { red[(t>>6)*2] = c0; red[(t>>6)*2 + 1] = c1; }
    }
    __syncthreads();
    if (t == 0) {
        float a0=0, a1=0;
        for (int w2 = 0; w2 < 8; ++w2) { a0 += red[w2*2]; a1 += red[w2*2+1]; }
        lbd_l[0] = fmaxf(a0, 0.0f);
        lbd_l[1] = fmaxf(a1, 0.0f);
    }
    __syncthreads();

    // ---------- x update (s1, s4) ----------
    if (t < KK) {
        float s1v = xb[KK + t];
        xb[KK + t]   = s1v - lbd_l[0] * (ALPHA / (1.0f + s1v));
        xb[4*KK + t] += lbd_l[1] * (ALPHA * VARTHETA);
    }
    __syncthreads();

    // ---------- A-fragments of hw (reused for 3 MFMA passes) ----------
    short8 A[4];
    #pragma unroll
    for (int kt = 0; kt < 4; ++kt)
        A[kt] = *(const short8*)&hwb[(wv*16 + lr)*HS + kt*32 + quad*8];

    // ---------- MFMA1: C2 = W0a_top + X2@W1a_bot + HW@W1a_top  -> c2T (bf16) ----------
    #pragma unroll
    for (int nt = 0; nt < 2; ++nt) {
        floatx4 acc = {0.f, 0.f, 0.f, 0.f};
        #pragma unroll
        for (int kt = 0; kt < 4; ++kt) {
            short8 bb = *(const short8*)&w1aT[(nt*16 + lr)*HS + kt*32 + quad*8];
            acc = __builtin_amdgcn_mfma_f32_16x16x32_bf16(A[kt], bb, acc, 0, 0, 0);
        }
        const int n = nt*16 + lr;
        ushort4 p4;
        unsigned short pe[4];
        #pragma unroll
        for (int r = 0; r < 4; ++r) {
            int mm = wv*16 + quad*4 + r;
            float v = acc[r] + g2_W0a[mm*32 + n];
            #pragma unroll
            for (int f = 0; f < 5; ++f) v += xb[f*KK + mm] * w1a2b[f*32 + n];
            pe[r] = f2bf(v);
        }
        p4.x = pe[0]; p4.y = pe[1]; p4.z = pe[2]; p4.w = pe[3];
        *(ushort4*)&c2T[n*HS + wv*16 + quad*4] = p4;
    }
    __syncthreads();

    // ---------- MFMA2: Z = relu(HW@C2 + X2@W0a_bot) -> zb (bf16, row-major) ----------
    #pragma unroll
    for (int nt = 0; nt < 2; ++nt) {
        floatx4 acc = {0.f, 0.f, 0.f, 0.f};
        #pragma unroll
        for (int kt = 0; kt < 4; ++kt) {
            short8 bb = *(const short8*)&c2T[(nt*16 + lr)*HS + kt*32 + quad*8];
            acc = __builtin_amdgcn_mfma_f32_16x16x32_bf16(A[kt], bb, acc, 0, 0, 0);
        }
        const int n = nt*16 + lr;
        #pragma unroll
        for (int r = 0; r < 4; ++r) {
            int mm = wv*16 + quad*4 + r;
            float v = acc[r];
            #pragma unroll
            for (int f = 0; f < 5; ++f) v += xb[f*KK + mm] * w0a2b[f*32 + n];
            zb[mm*ZS + n] = f2bf(fmaxf(v, 0.0f));
        }
    }
    __syncthreads();

    // ---------- E = Z@W1b2 (bf16 ->eT), t0 = Z@W0b2 (fp32 ->scr8) ----------
    {
        float ev[5] = {0,0,0,0,0}, t0v[5] = {0,0,0,0,0};
        #pragma unroll
        for (int hh = 0; hh < 8; ++hh) {
            int h = 8*g + hh;
            float zv = bf2f(zb[row*ZS + h]);
            #pragma unroll
            for (int c = 0; c < 5; ++c) {
                ev[c]  += zv * w1b2[h*5 + c];
                t0v[c] += zv * w0b2[h*5 + c];
            }
        }
        #pragma unroll
        for (int c = 0; c < 5; ++c) {
            ev[c]  += __shfl_xor(ev[c], 1);  ev[c]  += __shfl_xor(ev[c], 2);
            t0v[c] += __shfl_xor(t0v[c], 1); t0v[c] += __shfl_xor(t0v[c], 2);
        }
        if (g == 0) {
            #pragma unroll
            for (int c = 0; c < 5; ++c) {
                eT[c*HS + row] = f2bf(ev[c]);
                scr8[row*8 + c] = t0v[c];
            }
        }
    }
    __syncthreads();

    // ---------- tilde = t0 + HW@E ; x += tilde^T ----------
    {
        floatx4 acc = {0.f, 0.f, 0.f, 0.f};
        const int ns = lr < 5 ? lr : 4;
        #pragma unroll
        for (int kt = 0; kt < 4; ++kt) {
            short8 bb = *(const short8*)&eT[ns*HS + kt*32 + quad*8];
            acc = __builtin_amdgcn_mfma_f32_16x16x32_bf16(A[kt], bb, acc, 0, 0, 0);
        }
        if (lr < 5) {
            #pragma unroll
            for (int r = 0; r < 4; ++r) {
                int mm = wv*16 + quad*4 + r;
                xb[lr*KK + mm] += acc[r] + scr8[mm*8 + lr];
            }
        }
    }
    __syncthreads();

    // ---------- f = sum(x[:K]) - PMAX ----------
    float pv = (t < KK) ? xb[t] : 0.0f;
    #pragma unroll
    for (int s = 1; s < 64; s <<= 1) pv += __shfl_xor(pv, s);
    if ((t & 63) == 0) red[t >> 6] = pv;
    __syncthreads();
    if (t == 0) {
        float fs = 0.0f;
        for (int w2 = 0; w2 < 8; ++w2) fs += red[w2];
        fval_l = fs - PMAXV;
    }
    __syncthreads();

    const int num_itr = num_itr_p[0], kth = kth_p[0];
    const bool flag = (kth == num_itr - 1);
    const float nu3 = nu3_p[0], tg = tg_p[0];
    const float onu = 1.0f + nu3, otg = 1.0f + tg;
    const float Vnu = 1.0f - 1.0f/(onu*onu), Vg = 1.0f - 1.0f/(otg*otg);
    const float fv = fval_l;
    float* outx = out + (size_t)b * MM;

    #pragma unroll
    for (int r2 = 0; r2 < 2; ++r2) {
        int idx = r2*512 + t;
        if (idx < MM) {
            float v = xb[idx];
            if (idx < KK && fv > 0.0f) v -= fv * (1.0f/KK);
            v = fmaxf(v, (idx >= KK   && idx < 2*KK) ? nu3 : 0.0f);
            v = fminf(v, (idx >= 2*KK && idx < 3*KK) ? tg  : BIGV);
            v = fmaxf(v, (idx >= 3*KK && idx < 4*KK) ? Vnu : 0.0f);
            v = fminf(v, (idx >= 3*KK && idx < 4*KK) ? Vg  : BIGV);
            if (flag) v = fmaxf(v, 0.0f);
            xb[idx] = v;
            outx[idx] = v;
        }
    }
    __syncthreads();

    if (flag) {
        const size_t O1 = (size_t)B_N*MM;
        const size_t OK = (size_t)B_N*KK;
        if (t < KK) {
            float xg = xb[2*KK + t], xv = xb[3*KK + t];
            float u1 = 1.0f + xg;
            out[O1 + (size_t)b*KK + t]      = 1.0f - 1.0f/(u1*u1) - xv;   // f5
            out[O1 + OK + (size_t)b*KK + t] = sqrtf(xv) - xb[4*KK + t];   // f6
        }
        float dp = 0.0f;    // sum_i p[i]*hw[i][col=row]
        for (int w = 0; w < 32; ++w) {
            int i = 4*w + g;
            dp += xb[i] * bf2f(hwb[i*HS + row]);
        }
        dp += __shfl_xor(dp, 1); dp += __shfl_xor(dp, 2);
        if (g == 0) {
            float p = xb[row], nuv = xb[KK + row], xg = xb[2*KK + row];
            float diag = bf2f(hwb[row*HS + row]);
            float top = p * diag;
            float down = dp - top + 1.0f;
            out[O1 + 2*OK + (size_t)b*KK + row] = top - down * xg;        // f4
            out[O1 + 3*OK + (size_t)b*KK + row] = nuv * down - top;       // f2
        }
    }
}

extern "C" void kernel_launch(void* const* d_in, const int* in_sizes, int n_in,
                              void* d_out, int out_size, void* d_ws, size_t ws_size,
                              hipStream_t stream) {
    unfold_pocs_kernel<<<dim3(B_N), dim3(512), 0, stream>>>(
        (const int*)d_in[0], (const int*)d_in[1],
        (const float*)d_in[2], (const float*)d_in[3],
        (const float*)d_in[4], (const float*)d_in[5],
        (const float*)d_in[12], (const float*)d_in[13],
        (const float*)d_in[14], (const float*)d_in[15],
        (const float*)d_in[16], (const float*)d_in[17],
        (const float*)d_in[18], (const float*)d_in[19],
        (float*)d_out);
}